// Round 7
// baseline (149.778 us; speedup 1.0000x reference)
//
#include <hip/hip_runtime.h>
#include <hip/hip_bf16.h>

// SSIM loss, round 14: pass-2 staging via PLAIN LOADS -> VGPR -> ds_write.
// r13's split isolated the bottleneck: hblur (plain dense loads/stores) ran
// ~4.5-5 TB/s; vpass (global_load_lds of CONTIGUOUS 1KB, 4 tiles deep) sat
// at 1.3 TB/s and was equally slow fully-cache-resident (replay row: 51us at
// 0.7 GB/s HBM). Every slow variant r7-r13p2 staged via LDS-DMA or shallow
// reg loads; the fast pass uses plain global->VGPR. So: pass 2 now loads
// feat tiles into 4 rotating NAMED short8 register pairs (no arrays -> no
// scratch, r8/r9 lesson), ds_write_b128 into the same 16-slot ring, tile
// written 2 steps after issue (compiler emits counted vmcnt per tile).
// vstep/SSIM/reduce and the feat layout are verbatim r13.

typedef float  f32x4  __attribute__((ext_vector_type(4)));
typedef short  short8 __attribute__((ext_vector_type(8)));
typedef short  short4v __attribute__((ext_vector_type(4)));

__device__ __forceinline__ short bf16s(float x) {
    __hip_bfloat16 h = __float2bfloat16(x);
    return __builtin_bit_cast(short, h);
}
__device__ __forceinline__ float bf16f(float x) {
    unsigned u = (unsigned)__builtin_bit_cast(unsigned short,
                                              __float2bfloat16(x)) << 16;
    return __builtin_bit_cast(float, u);
}

#define SSIM_W_INIT const float W[11] = { \
    0.00102840f, 0.00759876f, 0.03600077f, 0.10936070f, 0.21300554f, \
    0.26601173f, \
    0.21300554f, 0.10936070f, 0.03600077f, 0.00759876f, 0.00102840f}

#define BW_INIT short8 bw; _Pragma("unroll") \
    for (int j = 0; j < 8; ++j) { \
        const int d = quad * 8 + j - n - 3; \
        bw[j] = bf16s((d >= 0 && d <= 10) ? W[d] : 0.f); \
    }

// ============================ PASS 1: hblur =============================
// (verbatim round 13 -- measured ~4.5-5 TB/s combined)
// grid 1024 = 32 img x 32 slabs (16 rows x 512 cols each).
// feat layout: [img][stripe32][tile32] blocks of 1024 shorts (2KB):
//   [grp2][feat4][col16][slot8] bf16  (grp = rows 8g..8g+7 of the tile)
__global__ __launch_bounds__(256, 2)
void ssim_hblur(const float* __restrict__ pred, const float* __restrict__ targ,
                unsigned short* __restrict__ feat) {
    SSIM_W_INIT;
    __shared__ __align__(16) short featLds[4][16][72][8];  // 73,728 B

    const int w = threadIdx.x >> 6, L = threadIdx.x & 63;
    const int n = L & 15, quad = L >> 4;
    const int img = blockIdx.x >> 5, T = blockIdx.x & 31;

    // zero granules 0 (cols [-8,0)) and 65 (cols [512,520))
    if (threadIdx.x < 128) {
        const int f = threadIdx.x >> 5, r = (threadIdx.x >> 1) & 15;
        const int gz = (threadIdx.x & 1) ? 65 : 0;
        const short8 z = {0, 0, 0, 0, 0, 0, 0, 0};
        *(short8*)&featLds[f][r][gz ^ (r & 7)][0] = z;
    }

    BW_INIT;
    const f32x4 zc = {0.f, 0.f, 0.f, 0.f};

    const size_t rowbase = (size_t)img * 262144 + (size_t)(16 * T + w * 4) * 512;
    const float* pr = pred + rowbase + 4 * L;
    const float* tr = targ + rowbase + 4 * L;
    const f32x4 pA0 = *(const f32x4*)(pr);
    const f32x4 pB0 = *(const f32x4*)(pr + 256);
    const f32x4 tA0 = *(const f32x4*)(tr);
    const f32x4 tB0 = *(const f32x4*)(tr + 256);
    const f32x4 pA1 = *(const f32x4*)(pr + 512);
    const f32x4 pB1 = *(const f32x4*)(pr + 768);
    const f32x4 tA1 = *(const f32x4*)(tr + 512);
    const f32x4 tB1 = *(const f32x4*)(tr + 768);
    const f32x4 pA2 = *(const f32x4*)(pr + 1024);
    const f32x4 pB2 = *(const f32x4*)(pr + 1280);
    const f32x4 tA2 = *(const f32x4*)(tr + 1024);
    const f32x4 tB2 = *(const f32x4*)(tr + 1280);
    const f32x4 pA3 = *(const f32x4*)(pr + 1536);
    const f32x4 pB3 = *(const f32x4*)(pr + 1792);
    const f32x4 tA3 = *(const f32x4*)(tr + 1536);
    const f32x4 tB3 = *(const f32x4*)(tr + 1792);

    const int gA = 1 + (L >> 1), gB = 33 + (L >> 1), hh = (L & 1) * 4;

#define P1ROW(k, PV, TV, QV, UV)                                          \
    {                                                                     \
        const int r = w * 4 + k;                                          \
        const int m = r & 7;                                              \
        short4v s0, s1, s2, s3, q0, q1, q2, q3;                           \
        _Pragma("unroll") for (int j = 0; j < 4; ++j) {                   \
            const float p = PV[j], t = TV[j];                             \
            const float u = p + t, v = p - t;                             \
            s0[j] = bf16s(p); s1[j] = bf16s(t);                           \
            s2[j] = bf16s(u * u); s3[j] = bf16s(v * v);                   \
            const float p2 = QV[j], t2 = UV[j];                           \
            const float u2 = p2 + t2, v2 = p2 - t2;                       \
            q0[j] = bf16s(p2); q1[j] = bf16s(t2);                         \
            q2[j] = bf16s(u2 * u2); q3[j] = bf16s(v2 * v2);               \
        }                                                                 \
        *(short4v*)&featLds[0][r][gA ^ m][hh] = s0;                       \
        *(short4v*)&featLds[1][r][gA ^ m][hh] = s1;                       \
        *(short4v*)&featLds[2][r][gA ^ m][hh] = s2;                       \
        *(short4v*)&featLds[3][r][gA ^ m][hh] = s3;                       \
        *(short4v*)&featLds[0][r][gB ^ m][hh] = q0;                       \
        *(short4v*)&featLds[1][r][gB ^ m][hh] = q1;                       \
        *(short4v*)&featLds[2][r][gB ^ m][hh] = q2;                       \
        *(short4v*)&featLds[3][r][gB ^ m][hh] = q3;                       \
    }
    P1ROW(0, pA0, tA0, pB0, tB0)
    P1ROW(1, pA1, tA1, pB1, tB1)
    P1ROW(2, pA2, tA2, pB2, tB2)
    P1ROW(3, pA3, tA3, pB3, tB3)
#undef P1ROW

    __syncthreads();

#pragma unroll
    for (int oi = 0; oi < 8; ++oi) {
        const int O = w * 8 + oi;
        unsigned short* dst = feat +
            ((size_t)(img * 32 + O) * 32 + T) * 1024 +
            (quad >> 1) * 512 + n * 8 + (quad & 1) * 4;
#pragma unroll
        for (int f = 0; f < 4; ++f) {
            const short8 af =
                *(const short8*)&featLds[f][n][(2 * O + quad) ^ (n & 7)][0];
            const f32x4 d = __builtin_amdgcn_mfma_f32_16x16x32_bf16(
                af, bw, zc, 0, 0, 0);
            short4v o;
#pragma unroll
            for (int r2 = 0; r2 < 4; ++r2) o[r2] = bf16s(d[r2]);
            *(short4v*)(dst + f * 128) = o;
        }
    }
}

// ======================= PASS 2: vblur + SSIM ===========================
// grid 512 x 256: wave = (img, q strip, stripe). Staging: plain global
// loads into rotating named short8 pairs -> ds_write_b128 into 16-slot
// ring. Tile written 2 steps after issue (~3 tiles in flight, counted
// vmcnt by compiler). No inline asm, no LDS-DMA, no barriers in compute.
__global__ __launch_bounds__(256, 2)
void ssim_vpass(const unsigned short* __restrict__ feat,
                float* __restrict__ slotSum, unsigned int* __restrict__ grpCnt,
                unsigned int* __restrict__ finalCnt, float* __restrict__ out) {
    SSIM_W_INIT;
    __shared__ __align__(16) char hbuf[4][16896];   // 16 slots x 1056 B
    __shared__ float wsum[4];

    const int w = threadIdx.x >> 6, L = threadIdx.x & 63;
    const int n = L & 15, quad = L >> 4;
    const int waveId = blockIdx.x * 4 + w;
    const int img = waveId >> 6, rem = waveId & 63;
    const int q = rem >> 5, stripe = rem & 31;
    const int s0 = q << 4;
    char* HB = &hbuf[w][0];

    float S = 0.f;
#pragma unroll
    for (int kk = 0; kk < 11; ++kk) S += bf16f(W[kk]);
    const float c2 = 1.0f / (S * S);
    BW_INIT;
    const f32x4 zc = {0.f, 0.f, 0.f, 0.f};
    const short8 z8 = {0, 0, 0, 0, 0, 0, 0, 0};

    const unsigned short* fbase = feat + (size_t)(img * 32 + stripe) * 32768;

    // tile index k = 0..16 <-> t = s0-1+k. Load: lane L takes 16B at L*16
    // of each 1KB half (solid 1KB/inst, per-wave stream fully sequential).
#define LOADK(R0, R1, k)                                                   \
    {                                                                      \
        const int t_ = s0 - 1 + (k);                                       \
        if ((unsigned)t_ <= 31u) {                                         \
            const unsigned short* sp_ = fbase + t_ * 1024 + L * 8;         \
            R0 = *(const short8*)sp_;                                      \
            R1 = *(const short8*)(sp_ + 512);                              \
        } else { R0 = z8; R1 = z8; }                                       \
    }
#define WRITEK(R0, R1, k)                                                  \
    {                                                                      \
        const int t_ = s0 - 1 + (k);                                       \
        *(short8*)(HB + ((2 * t_) & 15) * 1056 + L * 16) = R0;             \
        *(short8*)(HB + ((2 * t_ + 1) & 15) * 1056 + L * 16) = R1;         \
    }

    float lsum = 0.f;
    auto vstep = [&](int s) {
        f32x4 dv[4];
#pragma unroll
        for (int f = 0; f < 4; ++f) {
            const short8 af = *(const short8*)(
                HB + (size_t)((2 * s - 1 + quad) & 15) * 1056 + f * 256 + n * 16);
            dv[f] = __builtin_amdgcn_mfma_f32_16x16x32_bf16(af, bw, zc, 0, 0, 0);
        }
#pragma unroll
        for (int r = 0; r < 4; ++r) {
            const float m1 = dv[0][r] * c2, m2 = dv[1][r] * c2;
            const float Av = dv[2][r] * c2, Bv = dv[3][r] * c2;
            const float m12  = m1 * m2;
            const float smsq = m1 * m1 + m2 * m2;
            const float s12  = __builtin_fmaf(0.25f, Av - Bv, -m12);
            const float s1s2 = __builtin_fmaf(0.5f,  Av + Bv, -smsq);
            const float num = __builtin_fmaf(2.f, m12, 1e-4f) *
                              __builtin_fmaf(2.f, s12, 9e-4f);
            const float den = (smsq + 1e-4f) * (s1s2 + 9e-4f);
            float rc = __builtin_amdgcn_rcpf(den);
            rc = rc * (2.f - den * rc);
            lsum = __builtin_fmaf(num, rc, lsum);
        }
    };

    short8 A0, A1, B0, B1, C0, C1, D0, D1;

    // ---- prologue: tiles k=0..3 issued; k=0,1 written ----
    LOADK(A0, A1, 0)
    LOADK(B0, B1, 1)
    LOADK(C0, C1, 2)
    LOADK(D0, D1, 3)
    WRITEK(A0, A1, 0)
    WRITEK(B0, B1, 1)

    // ---- steady: 4 outer x 4 unrolled steps; step j: load k=4i+j+4 into
    //      R[j], write k=4i+j+2 from R[(j+2)%4], vstep(s0+4i+j) ----
#pragma unroll 1
    for (int i = 0; i < 4; ++i) {
        const int k4 = 4 * i;
        // j = 0: load A(k4+4), write C(k4+2)
        LOADK(A0, A1, k4 + 4)
        WRITEK(C0, C1, k4 + 2)
        vstep(s0 + k4);
        // j = 1: load B(k4+5), write D(k4+3)
        if (i < 3) { LOADK(B0, B1, k4 + 5) }
        WRITEK(D0, D1, k4 + 3)
        vstep(s0 + k4 + 1);
        // j = 2: load C(k4+6), write A(k4+4)
        if (i < 3) { LOADK(C0, C1, k4 + 6) }
        WRITEK(A0, A1, k4 + 4)
        vstep(s0 + k4 + 2);
        // j = 3: load D(k4+7), write B(k4+5)
        if (i < 3) { LOADK(D0, D1, k4 + 7) }
        WRITEK(B0, B1, k4 + 5)
        vstep(s0 + k4 + 3);
    }
#undef LOADK
#undef WRITEK

    // ---- hierarchical reduce (verbatim) ----
#pragma unroll
    for (int off = 32; off > 0; off >>= 1)
        lsum += __shfl_down(lsum, off, 64);
    if (L == 0) wsum[w] = lsum;
    __syncthreads();
    if (threadIdx.x == 0) {
        const float bs = wsum[0] + wsum[1] + wsum[2] + wsum[3];
        const int g = blockIdx.x & 63;           // 64 groups x 8 blocks
        atomicAdd(&slotSum[g * 16], bs);
        __threadfence();
        if (atomicAdd(&grpCnt[g * 16], 1u) == 7u) {
            __threadfence();
            if (atomicAdd(finalCnt, 1u) == 63u) {
                float s = 0.f;
#pragma unroll
                for (int i = 0; i < 64; ++i)
                    s += atomicAdd(&slotSum[i * 16], 0.f);
                out[0] = 1.0f - s * (1.0f / 8388608.0f);
            }
        }
    }
}

extern "C" void kernel_launch(void* const* d_in, const int* in_sizes, int n_in,
                              void* d_out, int out_size, void* d_ws,
                              size_t ws_size, hipStream_t stream) {
    const float* pred = (const float*)d_in[0];
    const float* targ = (const float*)d_in[1];
    // ws: [0,4096) slotSum @64B stride; [4096,8192) grpCnt; [8192,8196)
    // finalCnt; [65536, 65536+64MB) feat intermediate.
    float* slotSum = (float*)d_ws;
    unsigned int* grpCnt = (unsigned int*)((char*)d_ws + 4096);
    unsigned int* finalCnt = (unsigned int*)((char*)d_ws + 8192);

    hipMemsetAsync(d_ws, 0, 8196, stream);
    unsigned short* feat = (unsigned short*)((char*)d_ws + 65536);
    ssim_hblur<<<dim3(1024), dim3(256), 0, stream>>>(pred, targ, feat);
    ssim_vpass<<<dim3(512), dim3(256), 0, stream>>>(feat, slotSum, grpCnt,
                                                    finalCnt, (float*)d_out);
    (void)in_sizes; (void)n_in; (void)out_size; (void)ws_size;
}